// Round 14
// baseline (278.137 us; speedup 1.0000x reference)
//
#include <hip/hip_runtime.h>
#include <hip/hip_bf16.h>
#include <stdint.h>

#define N_B 4
#define SEQ 2048
#define NH 16
#define ED 128      // expanded feature dim per head
#define EMB 1024
#define FCK 2048    // NH*ED

typedef float f32x4 __attribute__((ext_vector_type(4)));
typedef float f32x16 __attribute__((ext_vector_type(16)));
typedef _Float16 f16x8 __attribute__((ext_vector_type(8)));
typedef _Float16 f16x4 __attribute__((ext_vector_type(4)));
typedef _Float16 f16x2 __attribute__((ext_vector_type(2)));
typedef __fp16 fp16v2 __attribute__((ext_vector_type(2)));

__device__ __forceinline__ void gload16(const void* g, void* l) {
    __builtin_amdgcn_global_load_lds(
        (const __attribute__((address_space(1))) uint32_t*)(g),
        (__attribute__((address_space(3))) uint32_t*)(l), 16, 0, 0);
}

__device__ __forceinline__ int pk2(float a, float b) {
    union { fp16v2 h; int i; } u;
    u.h = __builtin_amdgcn_cvt_pkrtz(a, b);
    return u.i;
}

__device__ __forceinline__ f16x2 asf16x2(int v) {
    union { int i; f16x2 h; } u; u.i = v; return u.h;
}

__device__ __forceinline__ f16x8 frag4(int d0, int d1, int d2, int d3) {
    union { int i[4]; f16x8 v; } u;
    u.i[0] = d0; u.i[1] = d1; u.i[2] = d2; u.i[3] = d3;
    return u.v;
}

// raw v_exp_f32 (inputs bounded <= 8; deep-negative -> 0 is correct)
__device__ __forceinline__ float ex2(float x) {
#if __has_builtin(__builtin_amdgcn_exp2f)
    return __builtin_amdgcn_exp2f(x);
#else
    return exp2f(x);
#endif
}

#define M3(a,b,c) fmaxf(fmaxf((a),(b)),(c))

// ---------------------------------------------------------------------------
// Kernel 1: feature map. One wave per (n,s); 16 heads = 16 MFMA rows.
// z via hi/lo fp16 split of x and fm_w (3-term) -> ~fp32-accurate z.
// Outputs (all [nh][s][128] fp16): qf (scaled log2e/32), kf, vf.
// ---------------------------------------------------------------------------
__global__ __launch_bounds__(256) void fmap_kernel(
    const float* __restrict__ vals, const float* __restrict__ keys,
    const float* __restrict__ qry,  const float* __restrict__ fmw,
    const float* __restrict__ fmb,
    _Float16* __restrict__ qf, _Float16* __restrict__ kf,
    _Float16* __restrict__ vf)
{
    const int lane = threadIdx.x & 63;
    const int w = threadIdx.x >> 6;
    const int t = blockIdx.x * 4 + w;      // (n*SEQ + s)
    const int n = t >> 11;
    const int s = t & 2047;
    const int r = lane & 15;
    const int g = lane >> 4;

    f16x8 whf[4][2], wlf[4][2];
    #pragma unroll
    for (int te = 0; te < 4; ++te) {
      #pragma unroll
      for (int j = 0; j < 2; ++j) {
        const float* p = fmw + (te*16 + r)*64 + j*32 + 8*g;
        #pragma unroll
        for (int i = 0; i < 8; ++i) {
            float wv = p[i];
            _Float16 hi = (_Float16)wv;
            whf[te][j][i] = hi;
            wlf[te][j][i] = (_Float16)(wv - (float)hi);
        }
      }
    }
    float bias[4];
    #pragma unroll
    for (int te = 0; te < 4; ++te) bias[te] = fmb[te*16 + r];

    const float QSCL = 0.03125f * 1.4426950408889634f;   // (1/sqrt(1024))*log2(e)

    const long rowoff = ((long)t*16 + r) * 64;
    const float* srcs[3] = {qry, keys, vals};
    #pragma unroll
    for (int tens = 0; tens < 3; ++tens) {
        const float* src = srcs[tens] + rowoff;
        f16x8 ah[2], al[2];
        #pragma unroll
        for (int j = 0; j < 2; ++j) {
            #pragma unroll
            for (int i = 0; i < 8; ++i) {
                float x = src[j*32 + 8*g + i];
                _Float16 hi = (_Float16)x;
                ah[j][i] = hi;
                al[j][i] = (_Float16)(x - (float)hi);
            }
        }
        #pragma unroll
        for (int te = 0; te < 4; ++te) {
            f32x4 c = (f32x4){0.f,0.f,0.f,0.f};
            c = __builtin_amdgcn_mfma_f32_16x16x32_f16(ah[0], whf[te][0], c, 0, 0, 0);
            c = __builtin_amdgcn_mfma_f32_16x16x32_f16(ah[1], whf[te][1], c, 0, 0, 0);
            c = __builtin_amdgcn_mfma_f32_16x16x32_f16(ah[0], wlf[te][0], c, 0, 0, 0);
            c = __builtin_amdgcn_mfma_f32_16x16x32_f16(ah[1], wlf[te][1], c, 0, 0, 0);
            c = __builtin_amdgcn_mfma_f32_16x16x32_f16(al[0], whf[te][0], c, 0, 0, 0);
            c = __builtin_amdgcn_mfma_f32_16x16x32_f16(al[1], whf[te][1], c, 0, 0, 0);
            #pragma unroll
            for (int i = 0; i < 4; ++i) {
                float z = c[i] + bias[te];
                float ep = __expf(z), en = __expf(-z);
                int hh = 4*g + i;
                int e = te*16 + r;
                long base = (((long)n*NH + hh)*SEQ + s)*ED;
                if (tens == 0) {
                    qf[base + e]      = (_Float16)(ep * QSCL);
                    qf[base + 64 + e] = (_Float16)(en * QSCL);
                } else if (tens == 1) {
                    kf[base + e]      = (_Float16)ep;
                    kf[base + 64 + e] = (_Float16)en;
                } else {
                    vf[base + e]      = (_Float16)ep;
                    vf[base + 64 + e] = (_Float16)en;
                }
            }
        }
    }
}

// ---------------------------------------------------------------------------
// Kernel 1b: vt[nh][e][s] = vf[nh][s][e] via 64x64 LDS tiles.
// ---------------------------------------------------------------------------
__global__ __launch_bounds__(256) void vtrans_kernel(
    const _Float16* __restrict__ vf, _Float16* __restrict__ vt)
{
    __shared__ _Float16 tile[64][72];
    const int b = blockIdx.x;          // nh*64 + st*2 + et
    const int et = b & 1;
    const int st = (b >> 1) & 31;
    const int nh = b >> 6;
    const _Float16* src = vf + ((long)nh*SEQ + st*64)*ED + et*64;
    const int col4 = (threadIdx.x & 15) * 4;
    const int row0 = threadIdx.x >> 4;
    #pragma unroll
    for (int j = 0; j < 4; ++j) {
        int row = row0 + j*16;
        *(f16x4*)&tile[row][col4] = *(const f16x4*)(src + (long)row*ED + col4);
    }
    __syncthreads();
    _Float16* dst = vt + ((long)nh*ED + et*64)*SEQ + st*64;
    const int erow = threadIdx.x >> 2;
    const int sc0 = (threadIdx.x & 3) * 16;
    f16x8 o0, o1;
    #pragma unroll
    for (int i = 0; i < 8; ++i) o0[i] = tile[sc0 + i][erow];
    #pragma unroll
    for (int i = 0; i < 8; ++i) o1[i] = tile[sc0 + 8 + i][erow];
    *(f16x8*)(dst + (long)erow*SEQ + sc0) = o0;
    *(f16x8*)(dst + (long)erow*SEQ + sc0 + 8) = o1;
}

// ---------------------------------------------------------------------------
// Kernel 2: fc_w fp32 -> fp16
// ---------------------------------------------------------------------------
__global__ __launch_bounds__(256) void cvt_kernel(
    const float* __restrict__ src, _Float16* __restrict__ dst)
{
    long i = ((long)blockIdx.x*256 + threadIdx.x)*8;
    f16x8 o;
    #pragma unroll
    for (int j = 0; j < 8; ++j) o[j] = (_Float16)src[i + j];
    *(f16x8*)(dst + i) = o;
}

// ---------------------------------------------------------------------------
// Kernel 3: flash attention, 32x32 MFMA structure.
// R14: 256-thread blocks (4 waves), KVBLK=64, 64KB LDS/block -> TWO
// independent blocks co-resident per CU. R11-R13 had one 8-wave block/CU:
// every __syncthreads+vmcnt drain stalled the whole CU (~23% neither-pipe
// idle). With 2 blocks/CU the barriers are per-block and de-correlated:
// while block A drains, block B's waves on the same SIMDs issue MFMA.
// Inner math identical to R11 (C-init=-mrun, relative defer-rescale THR=8,
// raw v_exp, packed-f16 rsum, permlane P-build).
// ---------------------------------------------------------------------------
__global__ __launch_bounds__(256, 2) void attn_kernel(
    const _Float16* __restrict__ qf,
    const _Float16* __restrict__ kf,
    const _Float16* __restrict__ vt,
    _Float16* __restrict__ ob)
{
    __shared__ char smem[65536];
    const int tid = threadIdx.x;
    const int lane = tid & 63;
    const int w = tid >> 6;                      // 0..3
    const int orig = blockIdx.x;                 // 1024 blocks
    const int b = ((orig & 7) << 7) | (orig >> 3);  // bijective XCD swizzle
    const int nh = b >> 4;
    const int n = nh >> 4, h = nh & 15;
    const int qt = (b & 15)*4 + w;               // 0..63, 32 q-rows each
    const int q32 = lane & 31;                   // q-col / A-row index
    const int hl = lane >> 5;                    // lane half

    const _Float16* qb = qf + (long)nh*SEQ*ED;
    const char* kg = (const char*)(kf + (long)nh*SEQ*ED);   // row = 256 B
    const char* vg = (const char*)(vt + (long)nh*ED*SEQ);   // row = SEQ*2 B

    // Q fragments (B-operand): lane holds Q[qt*32+q32][e = 16j + 8*hl + i]
    f16x8 qfr[8];
    #pragma unroll
    for (int j = 0; j < 8; ++j)
        qfr[j] = *(const f16x8*)(qb + (long)(qt*32 + q32)*ED + 16*j + 8*hl);

    // hoisted staging constants (kt-invariant)
    const long koff = (long)(tid >> 4)*256  + ((tid & 15) ^ ((tid >> 4) & 15))*16;
    const long voff = (long)(tid >> 3)*4096 + ((tid & 7) ^ ((tid >> 3) & 7))*16;
    const int  ldst = tid*16;

    // stage one 64-col K/V tile (K: 64 s-rows x 256B; V^T: 128 e-rows x 128B)
    auto stage = [&](int kt, int bsel) {
        char* Kl = smem + bsel*32768;
        char* Vl = Kl + 16384;
        const char* ksrc = kg + (long)kt*16384 + koff;   // kt*64 rows * 256B
        const char* vsrc = vg + (long)kt*128   + voff;   // kt*64 s * 2B
        #pragma unroll
        for (int i = 0; i < 4; ++i)
            gload16(ksrc + i*4096, Kl + i*4096 + ldst);  // 16 K-rows per round
        #pragma unroll
        for (int i = 0; i < 4; ++i)
            gload16(vsrc + (long)i*131072, Vl + i*4096 + ldst); // 32 e-rows/round
    };

    f32x16 acc[4];
    #pragma unroll
    for (int vv = 0; vv < 4; ++vv)
      #pragma unroll
      for (int i = 0; i < 16; ++i) acc[vv][i] = 0.f;
    float mrun = 0.f, lrun = 0.f;    // scores >= 0 (positive features)

    stage(0, 0);
    __syncthreads();

    const int kswz = q32 & 15;
    const int vswz = q32 & 7;

    for (int kt = 0; kt < SEQ/64; ++kt) {
        const int cur = kt & 1;
        if (kt + 1 < SEQ/64) stage(kt + 1, cur ^ 1);
        const char* Kl = smem + cur*32768;
        const char* Vl = Kl + 16384;

        // ---- QK^T: two 32x32 S^T tiles (k-rows 0-31, 32-63), C-init=-mrun ----
        const float nmr = -mrun;
        f32x16 s0, s1;
        #pragma unroll
        for (int i = 0; i < 16; ++i) { s0[i] = nmr; s1[i] = nmr; }
        const char* Kb = Kl + q32*256;
        __builtin_amdgcn_s_setprio(1);
        #pragma unroll
        for (int j = 0; j < 8; ++j) {
            int off = (((hl + 2*j) & 15) ^ kswz) << 4;
            f16x8 k0 = *(const f16x8*)(Kb + off);
            f16x8 k1 = *(const f16x8*)(Kb + 8192 + off);
            s0 = __builtin_amdgcn_mfma_f32_32x32x16_f16(k0, qfr[j], s0, 0, 0, 0);
            s1 = __builtin_amdgcn_mfma_f32_32x32x16_f16(k1, qfr[j], s1, 0, 0, 0);
        }
        __builtin_amdgcn_s_setprio(0);

        // ---- relative max, defer-rescale THR=8 ----
        float mx = M3(s0[0], s0[1], s0[2]);
        mx = M3(mx, s0[3], s0[4]);   mx = M3(mx, s0[5], s0[6]);
        mx = M3(mx, s0[7], s0[8]);   mx = M3(mx, s0[9], s0[10]);
        mx = M3(mx, s0[11], s0[12]); mx = M3(mx, s0[13], s0[14]);
        mx = M3(mx, s0[15], s1[0]);  mx = M3(mx, s1[1], s1[2]);
        mx = M3(mx, s1[3], s1[4]);   mx = M3(mx, s1[5], s1[6]);
        mx = M3(mx, s1[7], s1[8]);   mx = M3(mx, s1[9], s1[10]);
        mx = M3(mx, s1[11], s1[12]); mx = M3(mx, s1[13], s1[14]);
        mx = fmaxf(mx, s1[15]);
        mx = fmaxf(mx, __shfl_xor(mx, 32, 64));      // combine lane halves
        if (__any(mx > 8.0f)) {                       // rare path
            float d = fmaxf(mx, 0.f);
            float corr = ex2(-d);
            mrun += d;
            lrun *= corr;
            #pragma unroll
            for (int vv = 0; vv < 4; ++vv)
                #pragma unroll
                for (int i = 0; i < 16; ++i) acc[vv][i] *= corr;
            #pragma unroll
            for (int i = 0; i < 16; ++i) { s0[i] -= d; s1[i] -= d; }
        }
        // P = exp2(s_rel); rsum via packed f16 adds
        int wreg[2][8];
        f16x2 psum = (f16x2){(_Float16)0.f, (_Float16)0.f};
        #pragma unroll
        for (int tW = 0; tW < 8; ++tW) {
            int pw = pk2(ex2(s0[2*tW]), ex2(s0[2*tW+1]));
            wreg[0][tW] = pw; psum += asf16x2(pw);
        }
        #pragma unroll
        for (int tW = 0; tW < 8; ++tW) {
            int pw = pk2(ex2(s1[2*tW]), ex2(s1[2*tW+1]));
            wreg[1][tW] = pw; psum += asf16x2(pw);
        }
        float rsum = (float)psum[0] + (float)psum[1];
        rsum += __shfl_xor(rsum, 32, 64);
        lrun += rsum;

        // ---- build PV B-operands: permlane32_swap pairs ----
        f16x8 pa[4];
        #pragma unroll
        for (int kk = 0; kk < 2; ++kk) {
            #pragma unroll
            for (int par = 0; par < 2; ++par) {
                int a0 = wreg[kk][par*4 + 0], b0 = wreg[kk][par*4 + 2];
                int a1 = wreg[kk][par*4 + 1], b1 = wreg[kk][par*4 + 3];
                auto r0 = __builtin_amdgcn_permlane32_swap(a0, b0, false, false);
                auto r1 = __builtin_amdgcn_permlane32_swap(a1, b1, false, false);
                pa[kk*2 + par] = frag4(r0[0], r1[0], r0[1], r1[1]);
            }
        }

        // ---- PV: O^T += V^T · P  (4 ks slices × 4 v-subtiles) ----
        __builtin_amdgcn_s_setprio(1);
        #pragma unroll
        for (int ks = 0; ks < 4; ++ks) {
            f16x8 vfr[4];
            #pragma unroll
            for (int vv = 0; vv < 4; ++vv) {
                int vrow = vv*32 + q32;
                int c0 = ks*2 + hl;
                vfr[vv] = *(const f16x8*)(Vl + vrow*128 + ((c0 ^ vswz) << 4));
            }
            #pragma unroll
            for (int vv = 0; vv < 4; ++vv)
                acc[vv] = __builtin_amdgcn_mfma_f32_32x32x16_f16(vfr[vv], pa[ks], acc[vv], 0, 0, 0);
        }
        __builtin_amdgcn_s_setprio(0);

        __syncthreads();   // drains vmcnt (stage kt+1 done) + protects buffers
    }

    // ---- epilogue: O^T -> ob[n][q][h*128 + v] ----
    float inv = 1.0f / lrun;
    int q = qt*32 + q32;
    long base = ((long)n*SEQ + q)*FCK + h*ED;
    #pragma unroll
    for (int vv = 0; vv < 4; ++vv) {
        #pragma unroll
        for (int rg = 0; rg < 4; ++rg) {
            f16x4 o;
            #pragma unroll
            for (int i = 0; i < 4; ++i) o[i] = (_Float16)(acc[vv][rg*4 + i] * inv);
            *(f16x4*)(ob + base + vv*32 + 8*rg + 4*hl) = o;
        }
    }
}

// ---------------------------------------------------------------------------
// Kernel 4: out[8192,1024] = ob[8192,2048](fp16) @ fc_w^T(fp16) + fc_b, fp32.
// m97-style 128x128 tile, BK=32, double-buffered LDS via global_load_lds,
// XOR chunk swizzle. 4 waves (2x2), 64x64 per wave.
// ---------------------------------------------------------------------------
__global__ __launch_bounds__(256) void fc_kernel(
    const _Float16* __restrict__ ob,
    const _Float16* __restrict__ wt,
    const float* __restrict__ fcb,
    float* __restrict__ out)
{
    __shared__ char smem[32768];            // 2 x (A 8KB + B 8KB)
    const int lane = threadIdx.x & 63;
    const int w = threadIdx.x >> 6;         // 0..3
    const int wm = w >> 1, wn = w & 1;      // 2x2 wave grid
    const int r = lane & 15, g = lane >> 4;

    const int orig = blockIdx.x;            // 512 blocks
    const int tile = ((orig & 7) << 6) | (orig >> 3);  // XCD-contiguous
    const int mt = tile >> 3;               // 0..63
    const int nt = tile & 7;                // 0..7

    const char* Ag = (const char*)(ob + (long)mt*128*FCK);
    const char* Bg = (const char*)(wt + (long)nt*128*FCK);

    auto stage = [&](int kt, int bsel) {
        char* As = smem + bsel*16384;
        char* Bs = As + 8192;
        #pragma unroll
        for (int rnd = 0; rnd < 2; ++rnd) {
            int row = rnd*64 + w*16 + (lane >> 2);
            int cs = (lane & 3) ^ ((row >> 1) & 3);
            gload16(Ag + (long)row*(FCK*2) + kt*64 + cs*16, As + rnd*4096 + w*1024);
            gload16(Bg + (long)row*(FCK*2) + kt*64 + cs*16, Bs + rnd*4096 + w*1024);
        }
    };

    f32x4 acc[4][4];
    #pragma unroll
    for (int u = 0; u < 4; ++u)
      #pragma unroll
      for (int v = 0; v < 4; ++v) acc[u][v] = (f32x4){0.f,0.f,0.f,0.f};

    stage(0, 0);
    __syncthreads();

    for (int kt = 0; kt < FCK/32; ++kt) {
        const int cur = kt & 1;
        if (kt + 1 < FCK/32) stage(kt + 1, cur ^ 1);
        const char* As = smem + cur*16384;
        const char* Bs = As + 8192;

        f16x8 afr[4], bfr[4];
        #pragma unroll
        for (int u = 0; u < 4; ++u) {
            int row = wm*64 + u*16 + r;
            afr[u] = *(const f16x8*)(As + row*64 + ((g ^ ((row >> 1) & 3)) << 4));
        }
        #pragma unroll
        for (int v = 0; v < 4; ++v) {
            int row = wn*64 + v*16 + r;
            bfr[v] = *(const f16x8*)(Bs + row*64 + ((g ^ ((row >> 1) & 3)) << 4));
        }
        __builtin_amdgcn_s_setprio(1);
        #pragma unroll
        for (int u = 0; u < 4; ++u)
          #pragma unroll
          for (int v = 0; v < 4; ++v)
            acc[u][v] = __builtin_amdgcn_mfma_f32_16x16x32_f16(afr[u], bfr[v], acc[u][v], 0, 0, 0);
        __builtin_amdgcn_s_setprio(0);
        __syncthreads();
    }

    #pragma unroll
    for (int u = 0; u < 4; ++u)
      #pragma unroll
      for (int v = 0; v < 4; ++v) {
        int col = nt*128 + wn*64 + v*16 + r;
        float bias = fcb[col];
        #pragma unroll
        for (int i = 0; i < 4; ++i) {
            int row = mt*128 + wm*64 + u*16 + 4*g + i;
            out[(long)row*EMB + col] = acc[u][v][i] + bias;
        }
      }
}

// ---------------------------------------------------------------------------
extern "C" void kernel_launch(void* const* d_in, const int* in_sizes, int n_in,
                              void* d_out, int out_size, void* d_ws, size_t ws_size,
                              hipStream_t stream) {
    const float* vals = (const float*)d_in[0];
    const float* keys = (const float*)d_in[1];
    const float* qry  = (const float*)d_in[2];
    const float* fmw  = (const float*)d_in[3];
    const float* fmb  = (const float*)d_in[4];
    const float* fcw  = (const float*)d_in[5];
    const float* fcb  = (const float*)d_in[6];
    char* ws = (char*)d_ws;
    const long SZ = 33554432L;                       // 32 MB per fp16 tensor
    _Float16* qf = (_Float16*)(ws);
    _Float16* kf = (_Float16*)(ws + SZ);
    _Float16* vf = (_Float16*)(ws + 2*SZ);
    _Float16* vt = (_Float16*)(ws + 3*SZ);
    _Float16* ob = (_Float16*)(ws + 4*SZ);
    _Float16* wt = (_Float16*)(ws + 5*SZ);           // +4 MB
    float* out = (float*)d_out;

    fmap_kernel<<<dim3(2048), dim3(256), 0, stream>>>(vals, keys, qry, fmw, fmb, qf, kf, vf);
    vtrans_kernel<<<dim3(4096), dim3(256), 0, stream>>>(vf, vt);
    cvt_kernel<<<dim3(1024), dim3(256), 0, stream>>>(fcw, wt);
    attn_kernel<<<dim3(1024), dim3(256), 0, stream>>>(qf, kf, vt, ob);
    fc_kernel<<<dim3(512), dim3(256), 0, stream>>>(ob, wt, fcb, out);
}

// Round 15
// 266.349 us; speedup vs baseline: 1.0443x; 1.0443x over previous
//
#include <hip/hip_runtime.h>
#include <hip/hip_bf16.h>
#include <stdint.h>

#define N_B 4
#define SEQ 2048
#define NH 16
#define ED 128      // expanded feature dim per head
#define EMB 1024
#define FCK 2048    // NH*ED

typedef float f32x4 __attribute__((ext_vector_type(4)));
typedef float f32x16 __attribute__((ext_vector_type(16)));
typedef _Float16 f16x8 __attribute__((ext_vector_type(8)));
typedef _Float16 f16x4 __attribute__((ext_vector_type(4)));
typedef _Float16 f16x2 __attribute__((ext_vector_type(2)));
typedef __fp16 fp16v2 __attribute__((ext_vector_type(2)));

__device__ __forceinline__ void gload16(const void* g, void* l) {
    __builtin_amdgcn_global_load_lds(
        (const __attribute__((address_space(1))) uint32_t*)(g),
        (__attribute__((address_space(3))) uint32_t*)(l), 16, 0, 0);
}

__device__ __forceinline__ int pk2(float a, float b) {
    union { fp16v2 h; int i; } u;
    u.h = __builtin_amdgcn_cvt_pkrtz(a, b);
    return u.i;
}

__device__ __forceinline__ f16x2 asf16x2(int v) {
    union { int i; f16x2 h; } u; u.i = v; return u.h;
}

__device__ __forceinline__ f16x8 frag4(int d0, int d1, int d2, int d3) {
    union { int i[4]; f16x8 v; } u;
    u.i[0] = d0; u.i[1] = d1; u.i[2] = d2; u.i[3] = d3;
    return u.v;
}

// raw v_exp_f32 (inputs bounded; deep-negative -> 0 is correct)
__device__ __forceinline__ float ex2(float x) {
#if __has_builtin(__builtin_amdgcn_exp2f)
    return __builtin_amdgcn_exp2f(x);
#else
    return exp2f(x);
#endif
}

#define LOG2E 1.4426950408889634f
#define M3(a,b,c) fmaxf(fmaxf((a),(b)),(c))

// ---------------------------------------------------------------------------
// Kernel 1: feature map. One wave per (n,s); 16 heads = 16 MFMA rows.
// z via hi/lo fp16 split of x and fm_w (3-term) -> ~fp32-accurate z.
// exp via raw v_exp_f32 (ex2(z*log2e)); outputs qf (scaled log2e/32), kf, vf.
// ---------------------------------------------------------------------------
__global__ __launch_bounds__(256) void fmap_kernel(
    const float* __restrict__ vals, const float* __restrict__ keys,
    const float* __restrict__ qry,  const float* __restrict__ fmw,
    const float* __restrict__ fmb,
    _Float16* __restrict__ qf, _Float16* __restrict__ kf,
    _Float16* __restrict__ vf)
{
    const int lane = threadIdx.x & 63;
    const int w = threadIdx.x >> 6;
    const int t = blockIdx.x * 4 + w;      // (n*SEQ + s)
    const int n = t >> 11;
    const int s = t & 2047;
    const int r = lane & 15;
    const int g = lane >> 4;

    f16x8 whf[4][2], wlf[4][2];
    #pragma unroll
    for (int te = 0; te < 4; ++te) {
      #pragma unroll
      for (int j = 0; j < 2; ++j) {
        const float* p = fmw + (te*16 + r)*64 + j*32 + 8*g;
        #pragma unroll
        for (int i = 0; i < 8; ++i) {
            float wv = p[i];
            _Float16 hi = (_Float16)wv;
            whf[te][j][i] = hi;
            wlf[te][j][i] = (_Float16)(wv - (float)hi);
        }
      }
    }
    float bias[4];
    #pragma unroll
    for (int te = 0; te < 4; ++te) bias[te] = fmb[te*16 + r];

    const float QSCL = 0.03125f * LOG2E;   // (1/sqrt(1024))*log2(e)

    const long rowoff = ((long)t*16 + r) * 64;
    const float* srcs[3] = {qry, keys, vals};
    #pragma unroll
    for (int tens = 0; tens < 3; ++tens) {
        const float* src = srcs[tens] + rowoff;
        f16x8 ah[2], al[2];
        #pragma unroll
        for (int j = 0; j < 2; ++j) {
            #pragma unroll
            for (int i = 0; i < 8; ++i) {
                float x = src[j*32 + 8*g + i];
                _Float16 hi = (_Float16)x;
                ah[j][i] = hi;
                al[j][i] = (_Float16)(x - (float)hi);
            }
        }
        #pragma unroll
        for (int te = 0; te < 4; ++te) {
            f32x4 c = (f32x4){0.f,0.f,0.f,0.f};
            c = __builtin_amdgcn_mfma_f32_16x16x32_f16(ah[0], whf[te][0], c, 0, 0, 0);
            c = __builtin_amdgcn_mfma_f32_16x16x32_f16(ah[1], whf[te][1], c, 0, 0, 0);
            c = __builtin_amdgcn_mfma_f32_16x16x32_f16(ah[0], wlf[te][0], c, 0, 0, 0);
            c = __builtin_amdgcn_mfma_f32_16x16x32_f16(ah[1], wlf[te][1], c, 0, 0, 0);
            c = __builtin_amdgcn_mfma_f32_16x16x32_f16(al[0], whf[te][0], c, 0, 0, 0);
            c = __builtin_amdgcn_mfma_f32_16x16x32_f16(al[1], whf[te][1], c, 0, 0, 0);
            #pragma unroll
            for (int i = 0; i < 4; ++i) {
                float zl = (c[i] + bias[te]) * LOG2E;
                float ep = ex2(zl), en = ex2(-zl);
                int hh = 4*g + i;
                int e = te*16 + r;
                long base = (((long)n*NH + hh)*SEQ + s)*ED;
                if (tens == 0) {
                    qf[base + e]      = (_Float16)(ep * QSCL);
                    qf[base + 64 + e] = (_Float16)(en * QSCL);
                } else if (tens == 1) {
                    kf[base + e]      = (_Float16)ep;
                    kf[base + 64 + e] = (_Float16)en;
                } else {
                    vf[base + e]      = (_Float16)ep;
                    vf[base + 64 + e] = (_Float16)en;
                }
            }
        }
    }
}

// ---------------------------------------------------------------------------
// Kernel 1b: vt[nh][e][s] = vf[nh][s][e] via 64x64 LDS tiles.
// ---------------------------------------------------------------------------
__global__ __launch_bounds__(256) void vtrans_kernel(
    const _Float16* __restrict__ vf, _Float16* __restrict__ vt)
{
    __shared__ _Float16 tile[64][72];
    const int b = blockIdx.x;          // nh*64 + st*2 + et
    const int et = b & 1;
    const int st = (b >> 1) & 31;
    const int nh = b >> 6;
    const _Float16* src = vf + ((long)nh*SEQ + st*64)*ED + et*64;
    const int col4 = (threadIdx.x & 15) * 4;
    const int row0 = threadIdx.x >> 4;
    #pragma unroll
    for (int j = 0; j < 4; ++j) {
        int row = row0 + j*16;
        *(f16x4*)&tile[row][col4] = *(const f16x4*)(src + (long)row*ED + col4);
    }
    __syncthreads();
    _Float16* dst = vt + ((long)nh*ED + et*64)*SEQ + st*64;
    const int erow = threadIdx.x >> 2;
    const int sc0 = (threadIdx.x & 3) * 16;
    f16x8 o0, o1;
    #pragma unroll
    for (int i = 0; i < 8; ++i) o0[i] = tile[sc0 + i][erow];
    #pragma unroll
    for (int i = 0; i < 8; ++i) o1[i] = tile[sc0 + 8 + i][erow];
    *(f16x8*)(dst + (long)erow*SEQ + sc0) = o0;
    *(f16x8*)(dst + (long)erow*SEQ + sc0 + 8) = o1;
}

// ---------------------------------------------------------------------------
// Kernel 2: fc_w fp32 -> fp16
// ---------------------------------------------------------------------------
__global__ __launch_bounds__(256) void cvt_kernel(
    const float* __restrict__ src, _Float16* __restrict__ dst)
{
    long i = ((long)blockIdx.x*256 + threadIdx.x)*8;
    f16x8 o;
    #pragma unroll
    for (int j = 0; j < 8; ++j) o[j] = (_Float16)src[i + j];
    *(f16x8*)(dst + i) = o;
}

// ---------------------------------------------------------------------------
// Kernel 3: flash attention, 32x32 MFMA structure, KVBLK=128.
// EXACT revert to the best-measured config (R11, 158 us): 512-thr blocks,
// C-init=-mrun, relative defer-rescale THR=8, raw v_exp, packed-f16 rsum,
// permlane P-build. R12-R14 scheduling/structural variants were all
// neutral-to-worse -> this is the structural plateau (~870 TF).
// ---------------------------------------------------------------------------
__global__ __launch_bounds__(512, 2) void attn_kernel(
    const _Float16* __restrict__ qf,
    const _Float16* __restrict__ kf,
    const _Float16* __restrict__ vt,
    _Float16* __restrict__ ob)
{
    __shared__ char smem[131072];
    const int tid = threadIdx.x;
    const int lane = tid & 63;
    const int w = tid >> 6;                      // 0..7
    const int orig = blockIdx.x;                 // 512 blocks
    const int b = ((orig & 7) << 6) | (orig >> 3);  // bijective XCD swizzle
    const int nh = b >> 3;
    const int n = nh >> 4, h = nh & 15;
    const int qt = (b & 7)*8 + w;                // 0..63, 32 q-rows each
    const int q32 = lane & 31;                   // q-col / A-row index
    const int hl = lane >> 5;                    // lane half

    const _Float16* qb = qf + (long)nh*SEQ*ED;
    const char* kg = (const char*)(kf + (long)nh*SEQ*ED);   // row = 256 B
    const char* vg = (const char*)(vt + (long)nh*ED*SEQ);   // row = SEQ*2 B

    // Q fragments (B-operand): lane holds Q[qt*32+q32][e = 16j + 8*hl + i]
    f16x8 qfr[8];
    #pragma unroll
    for (int j = 0; j < 8; ++j)
        qfr[j] = *(const f16x8*)(qb + (long)(qt*32 + q32)*ED + 16*j + 8*hl);

    // hoisted staging constants (kt-invariant)
    const int srow = tid >> 4;                         // 0..31
    const int sc   = (tid & 15) ^ (srow & 15);         // XOR chunk swizzle
    const long koff = (long)srow*256  + sc*16;         // + i*8192 per round
    const long voff = (long)srow*4096 + sc*16;         // + i*131072 per round
    const int  ldst = tid*16;                          // + i*8192 per round

    // stage one 128-col K/V tile (K: 128 s-rows x 256B; V: 128 e-rows x 256B)
    auto stage = [&](int kt, int bsel) {
        char* Kl = smem + bsel*65536;
        char* Vl = Kl + 32768;
        const char* ksrc = kg + (long)kt*32768 + koff;
        const char* vsrc = vg + (long)kt*256   + voff;
        #pragma unroll
        for (int i = 0; i < 4; ++i)
            gload16(ksrc + i*8192, Kl + i*8192 + ldst);
        #pragma unroll
        for (int i = 0; i < 4; ++i)
            gload16(vsrc + (long)i*131072, Vl + i*8192 + ldst);
    };

    f32x16 acc[4];
    #pragma unroll
    for (int vv = 0; vv < 4; ++vv)
      #pragma unroll
      for (int i = 0; i < 16; ++i) acc[vv][i] = 0.f;
    float mrun = 0.f, lrun = 0.f;    // scores >= 0 (positive features)

    stage(0, 0);
    __syncthreads();

    const int kswz = q32 & 15;

    for (int kt = 0; kt < SEQ/128; ++kt) {
        const int cur = kt & 1;
        if (kt + 1 < SEQ/128) stage(kt + 1, cur ^ 1);
        const char* Kl = smem + cur*65536;
        const char* Vl = Kl + 32768;

        #pragma unroll
        for (int p = 0; p < 2; ++p) {
            // ---- QK^T: two 32x32 S^T tiles, C-init = -mrun ----
            const float nmr = -mrun;
            f32x16 s0, s1;
            #pragma unroll
            for (int i = 0; i < 16; ++i) { s0[i] = nmr; s1[i] = nmr; }
            const char* Kb = Kl + (p*64 + q32)*256;
            __builtin_amdgcn_s_setprio(1);
            #pragma unroll
            for (int j = 0; j < 8; ++j) {
                int off = (((hl + 2*j) & 15) ^ kswz) << 4;
                f16x8 k0 = *(const f16x8*)(Kb + off);
                f16x8 k1 = *(const f16x8*)(Kb + 8192 + off);
                s0 = __builtin_amdgcn_mfma_f32_32x32x16_f16(k0, qfr[j], s0, 0, 0, 0);
                s1 = __builtin_amdgcn_mfma_f32_32x32x16_f16(k1, qfr[j], s1, 0, 0, 0);
            }
            __builtin_amdgcn_s_setprio(0);

            // ---- relative max, defer-rescale THR=8 ----
            float mx = M3(s0[0], s0[1], s0[2]);
            mx = M3(mx, s0[3], s0[4]);   mx = M3(mx, s0[5], s0[6]);
            mx = M3(mx, s0[7], s0[8]);   mx = M3(mx, s0[9], s0[10]);
            mx = M3(mx, s0[11], s0[12]); mx = M3(mx, s0[13], s0[14]);
            mx = M3(mx, s0[15], s1[0]);  mx = M3(mx, s1[1], s1[2]);
            mx = M3(mx, s1[3], s1[4]);   mx = M3(mx, s1[5], s1[6]);
            mx = M3(mx, s1[7], s1[8]);   mx = M3(mx, s1[9], s1[10]);
            mx = M3(mx, s1[11], s1[12]); mx = M3(mx, s1[13], s1[14]);
            mx = fmaxf(mx, s1[15]);
            mx = fmaxf(mx, __shfl_xor(mx, 32, 64));      // combine lane halves
            if (__any(mx > 8.0f)) {                       // rare path
                float d = fmaxf(mx, 0.f);
                float corr = ex2(-d);
                mrun += d;
                lrun *= corr;
                #pragma unroll
                for (int vv = 0; vv < 4; ++vv)
                    #pragma unroll
                    for (int i = 0; i < 16; ++i) acc[vv][i] *= corr;
                #pragma unroll
                for (int i = 0; i < 16; ++i) { s0[i] -= d; s1[i] -= d; }
            }
            // P = exp2(s_rel); rsum via packed f16 adds
            int wreg[2][8];
            f16x2 psum = (f16x2){(_Float16)0.f, (_Float16)0.f};
            #pragma unroll
            for (int tW = 0; tW < 8; ++tW) {
                int pw = pk2(ex2(s0[2*tW]), ex2(s0[2*tW+1]));
                wreg[0][tW] = pw; psum += asf16x2(pw);
            }
            #pragma unroll
            for (int tW = 0; tW < 8; ++tW) {
                int pw = pk2(ex2(s1[2*tW]), ex2(s1[2*tW+1]));
                wreg[1][tW] = pw; psum += asf16x2(pw);
            }
            float rsum = (float)psum[0] + (float)psum[1];
            rsum += __shfl_xor(rsum, 32, 64);
            lrun += rsum;

            // ---- build PV B-operands: permlane32_swap pairs ----
            f16x8 pa[4];
            #pragma unroll
            for (int kk = 0; kk < 2; ++kk) {
                #pragma unroll
                for (int par = 0; par < 2; ++par) {
                    int a0 = wreg[kk][par*4 + 0], b0 = wreg[kk][par*4 + 2];
                    int a1 = wreg[kk][par*4 + 1], b1 = wreg[kk][par*4 + 3];
                    auto r0 = __builtin_amdgcn_permlane32_swap(a0, b0, false, false);
                    auto r1 = __builtin_amdgcn_permlane32_swap(a1, b1, false, false);
                    pa[kk*2 + par] = frag4(r0[0], r1[0], r0[1], r1[1]);
                }
            }

            // ---- PV: O^T += V^T · P  (4 ks slices × 4 v-subtiles) ----
            #pragma unroll
            for (int ks = 0; ks < 4; ++ks) {
                f16x8 vfr[4];
                #pragma unroll
                for (int vv = 0; vv < 4; ++vv) {
                    int vrow = vv*32 + q32;
                    int c0 = p*8 + ks*2 + hl;
                    vfr[vv] = *(const f16x8*)(Vl + vrow*256 + ((c0 ^ kswz) << 4));
                }
                __builtin_amdgcn_s_setprio(1);
                #pragma unroll
                for (int vv = 0; vv < 4; ++vv)
                    acc[vv] = __builtin_amdgcn_mfma_f32_32x32x16_f16(vfr[vv], pa[ks], acc[vv], 0, 0, 0);
                __builtin_amdgcn_s_setprio(0);
            }
        }
        __syncthreads();   // drains vmcnt (stage kt+1 done) + protects buffers
    }

    // ---- epilogue: O^T -> ob[n][q][h*128 + v] ----
    float inv = 1.0f / lrun;
    int q = qt*32 + q32;
    long base = ((long)n*SEQ + q)*FCK + h*ED;
    #pragma unroll
    for (int vv = 0; vv < 4; ++vv) {
        #pragma unroll
        for (int rg = 0; rg < 4; ++rg) {
            f16x4 o;
            #pragma unroll
            for (int i = 0; i < 4; ++i) o[i] = (_Float16)(acc[vv][rg*4 + i] * inv);
            *(f16x4*)(ob + base + vv*32 + 8*rg + 4*hl) = o;
        }
    }
}

// ---------------------------------------------------------------------------
// Kernel 4: out[8192,1024] = ob[8192,2048](fp16) @ fc_w^T(fp16) + fc_b, fp32.
// 128x128 tile, BK=64 (half the barriers of BK=32; LDS dbuf 64KB -> still
// 2 blocks/CU). Swizzle: store chunk c^(row&7), read chunk (g+4kk)^(row&7)
// -> <=2-way conflicts (free). 4 waves (2x2), 64x64 per wave.
// ---------------------------------------------------------------------------
__global__ __launch_bounds__(256) void fc_kernel(
    const _Float16* __restrict__ ob,
    const _Float16* __restrict__ wt,
    const float* __restrict__ fcb,
    float* __restrict__ out)
{
    __shared__ char smem[65536];            // 2 x (A 16KB + B 16KB)
    const int tid = threadIdx.x;
    const int lane = tid & 63;
    const int w = tid >> 6;                 // 0..3
    const int wm = w >> 1, wn = w & 1;      // 2x2 wave grid
    const int r = lane & 15, g = lane >> 4;

    const int orig = blockIdx.x;            // 512 blocks
    const int tile = ((orig & 7) << 6) | (orig >> 3);  // XCD-contiguous
    const int mt = tile >> 3;               // 0..63
    const int nt = tile & 7;                // 0..7

    const char* Ag = (const char*)(ob + (long)mt*128*FCK);
    const char* Bg = (const char*)(wt + (long)nt*128*FCK);

    // staging constants: thread t covers row rnd*32+(t>>3), chunk t&7
    const int srow = tid >> 3;              // 0..31 (row within round)
    const int schk = tid & 7;
    const int  ldst = tid*16;               // + rnd*4096
    const long goff = (long)srow*(FCK*2) + (schk ^ (srow & 7))*16;

    auto stage = [&](int kt, int bsel) {
        char* As = smem + bsel*32768;
        char* Bs = As + 16384;
        const char* asrc = Ag + (long)kt*128 + goff;
        const char* bsrc = Bg + (long)kt*128 + goff;
        #pragma unroll
        for (int rnd = 0; rnd < 4; ++rnd)
            gload16(asrc + (long)rnd*32*(FCK*2), As + rnd*4096 + ldst);
        #pragma unroll
        for (int rnd = 0; rnd < 4; ++rnd)
            gload16(bsrc + (long)rnd*32*(FCK*2), Bs + rnd*4096 + ldst);
    };

    f32x4 acc[4][4];
    #pragma unroll
    for (int u = 0; u < 4; ++u)
      #pragma unroll
      for (int v = 0; v < 4; ++v) acc[u][v] = (f32x4){0.f,0.f,0.f,0.f};

    stage(0, 0);
    __syncthreads();

    for (int kt = 0; kt < FCK/64; ++kt) {
        const int cur = kt & 1;
        if (kt + 1 < FCK/64) stage(kt + 1, cur ^ 1);
        const char* As = smem + cur*32768;
        const char* Bs = As + 16384;

        #pragma unroll
        for (int kk = 0; kk < 2; ++kk) {
            f16x8 afr[4], bfr[4];
            #pragma unroll
            for (int u = 0; u < 4; ++u) {
                int row = wm*64 + u*16 + r;
                afr[u] = *(const f16x8*)(As + row*128 + (((g + 4*kk) ^ (row & 7)) << 4));
            }
            #pragma unroll
            for (int v = 0; v < 4; ++v) {
                int row = wn*64 + v*16 + r;
                bfr[v] = *(const f16x8*)(Bs + row*128 + (((g + 4*kk) ^ (row & 7)) << 4));
            }
            __builtin_amdgcn_s_setprio(1);
            #pragma unroll
            for (int u = 0; u < 4; ++u)
              #pragma unroll
              for (int v = 0; v < 4; ++v)
                acc[u][v] = __builtin_amdgcn_mfma_f32_16x16x32_f16(afr[u], bfr[v], acc[u][v], 0, 0, 0);
            __builtin_amdgcn_s_setprio(0);
        }
        __syncthreads();
    }

    #pragma unroll
    for (int u = 0; u < 4; ++u)
      #pragma unroll
      for (int v = 0; v < 4; ++v) {
        int col = nt*128 + wn*64 + v*16 + r;
        float bias = fcb[col];
        #pragma unroll
        for (int i = 0; i < 4; ++i) {
            int row = mt*128 + wm*64 + u*16 + 4*g + i;
            out[(long)row*EMB + col] = acc[u][v][i] + bias;
        }
      }
}

// ---------------------------------------------------------------------------
extern "C" void kernel_launch(void* const* d_in, const int* in_sizes, int n_in,
                              void* d_out, int out_size, void* d_ws, size_t ws_size,
                              hipStream_t stream) {
    const float* vals = (const float*)d_in[0];
    const float* keys = (const float*)d_in[1];
    const float* qry  = (const float*)d_in[2];
    const float* fmw  = (const float*)d_in[3];
    const float* fmb  = (const float*)d_in[4];
    const float* fcw  = (const float*)d_in[5];
    const float* fcb  = (const float*)d_in[6];
    char* ws = (char*)d_ws;
    const long SZ = 33554432L;                       // 32 MB per fp16 tensor
    _Float16* qf = (_Float16*)(ws);
    _Float16* kf = (_Float16*)(ws + SZ);
    _Float16* vf = (_Float16*)(ws + 2*SZ);
    _Float16* vt = (_Float16*)(ws + 3*SZ);
    _Float16* ob = (_Float16*)(ws + 4*SZ);
    _Float16* wt = (_Float16*)(ws + 5*SZ);           // +4 MB
    float* out = (float*)d_out;

    fmap_kernel<<<dim3(2048), dim3(256), 0, stream>>>(vals, keys, qry, fmw, fmb, qf, kf, vf);
    vtrans_kernel<<<dim3(4096), dim3(256), 0, stream>>>(vf, vt);
    cvt_kernel<<<dim3(1024), dim3(256), 0, stream>>>(fcw, wt);
    attn_kernel<<<dim3(512), dim3(512), 0, stream>>>(qf, kf, vt, ob);
    fc_kernel<<<dim3(512), dim3(256), 0, stream>>>(ob, wt, fcb, out);
}

// Round 16
// 246.897 us; speedup vs baseline: 1.1265x; 1.0788x over previous
//
#include <hip/hip_runtime.h>
#include <hip/hip_bf16.h>
#include <stdint.h>

#define N_B 4
#define SEQ 2048
#define NH 16
#define ED 128      // expanded feature dim per head
#define EMB 1024
#define FCK 2048    // NH*ED

typedef float f32x4 __attribute__((ext_vector_type(4)));
typedef float f32x16 __attribute__((ext_vector_type(16)));
typedef _Float16 f16x8 __attribute__((ext_vector_type(8)));
typedef _Float16 f16x4 __attribute__((ext_vector_type(4)));
typedef _Float16 f16x2 __attribute__((ext_vector_type(2)));
typedef __fp16 fp16v2 __attribute__((ext_vector_type(2)));

__device__ __forceinline__ void gload16(const void* g, void* l) {
    __builtin_amdgcn_global_load_lds(
        (const __attribute__((address_space(1))) uint32_t*)(g),
        (__attribute__((address_space(3))) uint32_t*)(l), 16, 0, 0);
}

__device__ __forceinline__ int pk2(float a, float b) {
    union { fp16v2 h; int i; } u;
    u.h = __builtin_amdgcn_cvt_pkrtz(a, b);
    return u.i;
}

__device__ __forceinline__ f16x2 asf16x2(int v) {
    union { int i; f16x2 h; } u; u.i = v; return u.h;
}

__device__ __forceinline__ f16x8 frag4(int d0, int d1, int d2, int d3) {
    union { int i[4]; f16x8 v; } u;
    u.i[0] = d0; u.i[1] = d1; u.i[2] = d2; u.i[3] = d3;
    return u.v;
}

// raw v_exp_f32 (inputs bounded; deep-negative -> 0 is correct)
__device__ __forceinline__ float ex2(float x) {
#if __has_builtin(__builtin_amdgcn_exp2f)
    return __builtin_amdgcn_exp2f(x);
#else
    return exp2f(x);
#endif
}

#define LOG2E 1.4426950408889634f
#define M3(a,b,c) fmaxf(fmaxf((a),(b)),(c))

// ---------------------------------------------------------------------------
// Kernel 1: feature map + inline V transpose. One block = (n, head, 64-s
// tile); wave w owns 16 s-rows. A-rows = s (x[(n,s)][h*64+d], 256B/row);
// B = fm_w hi/lo (shared across heads). z ~fp32-exact via 3-term hi/lo MFMA.
// qf/kf written direct (s-major rows, as before). V features staged in a
// padded LDS tile [64 s][136 e] and written out transposed as full 128-B
// vt rows -> the separate vtrans kernel (128 MB of traffic) is eliminated.
// ---------------------------------------------------------------------------
__global__ __launch_bounds__(256) void fmap_kernel(
    const float* __restrict__ vals, const float* __restrict__ keys,
    const float* __restrict__ qry,  const float* __restrict__ fmw,
    const float* __restrict__ fmb,
    _Float16* __restrict__ qf, _Float16* __restrict__ kf,
    _Float16* __restrict__ vt)
{
    __shared__ _Float16 vtile[64][136];
    const int tid = threadIdx.x;
    const int lane = tid & 63;
    const int w = tid >> 6;            // 0..3
    const int b = blockIdx.x;          // 2048 = n(4) x h(16) x st(32)
    const int st = b & 31;
    const int h  = (b >> 5) & 15;
    const int n  = b >> 9;
    const int r = lane & 15;
    const int g = lane >> 4;

    f16x8 whf[4][2], wlf[4][2];
    #pragma unroll
    for (int te = 0; te < 4; ++te) {
      #pragma unroll
      for (int j = 0; j < 2; ++j) {
        const float* p = fmw + (te*16 + r)*64 + j*32 + 8*g;
        #pragma unroll
        for (int i = 0; i < 8; ++i) {
            float wv = p[i];
            _Float16 hi = (_Float16)wv;
            whf[te][j][i] = hi;
            wlf[te][j][i] = (_Float16)(wv - (float)hi);
        }
      }
    }
    float bias[4];
    #pragma unroll
    for (int te = 0; te < 4; ++te) bias[te] = fmb[te*16 + r];

    const float QSCL = 0.03125f * LOG2E;   // (1/sqrt(1024))*log2(e)

    const int s0 = st*64 + w*16;           // wave's s base
    const long rowoff = ((long)n*SEQ + s0 + r)*EMB + h*64;
    const float* srcs[3] = {qry, keys, vals};
    #pragma unroll
    for (int tens = 0; tens < 3; ++tens) {
        const float* src = srcs[tens] + rowoff;
        f16x8 ah[2], al[2];
        #pragma unroll
        for (int j = 0; j < 2; ++j) {
            #pragma unroll
            for (int i = 0; i < 8; ++i) {
                float x = src[j*32 + 8*g + i];
                _Float16 hi = (_Float16)x;
                ah[j][i] = hi;
                al[j][i] = (_Float16)(x - (float)hi);
            }
        }
        #pragma unroll
        for (int te = 0; te < 4; ++te) {
            f32x4 c = (f32x4){0.f,0.f,0.f,0.f};
            c = __builtin_amdgcn_mfma_f32_16x16x32_f16(ah[0], whf[te][0], c, 0, 0, 0);
            c = __builtin_amdgcn_mfma_f32_16x16x32_f16(ah[1], whf[te][1], c, 0, 0, 0);
            c = __builtin_amdgcn_mfma_f32_16x16x32_f16(ah[0], wlf[te][0], c, 0, 0, 0);
            c = __builtin_amdgcn_mfma_f32_16x16x32_f16(ah[1], wlf[te][1], c, 0, 0, 0);
            c = __builtin_amdgcn_mfma_f32_16x16x32_f16(al[0], whf[te][0], c, 0, 0, 0);
            c = __builtin_amdgcn_mfma_f32_16x16x32_f16(al[1], whf[te][1], c, 0, 0, 0);
            // lane holds z[s-row = 4g+i][e = te*16 + r]
            #pragma unroll
            for (int i = 0; i < 4; ++i) {
                float zl = (c[i] + bias[te]) * LOG2E;
                float ep = ex2(zl), en = ex2(-zl);
                int e = te*16 + r;
                int srow = 4*g + i;
                if (tens == 2) {
                    vtile[w*16 + srow][e]      = (_Float16)ep;
                    vtile[w*16 + srow][64 + e] = (_Float16)en;
                } else {
                    long base = (((long)(n*NH + h))*SEQ + s0 + srow)*ED;
                    if (tens == 0) {
                        qf[base + e]      = (_Float16)(ep * QSCL);
                        qf[base + 64 + e] = (_Float16)(en * QSCL);
                    } else {
                        kf[base + e]      = (_Float16)ep;
                        kf[base + 64 + e] = (_Float16)en;
                    }
                }
            }
        }
    }

    __syncthreads();
    // cooperative transposed write: vt[(n,h)][e][st*64 + s], full 128-B rows
    const int e  = tid >> 1;           // 0..127
    const int sh = tid & 1;            // 0/1 -> s-half
    _Float16* dst = vt + ((long)(n*NH + h)*ED + e)*SEQ + st*64 + sh*32;
    #pragma unroll
    for (int cchunk = 0; cchunk < 4; ++cchunk) {
        f16x8 o;
        #pragma unroll
        for (int j = 0; j < 8; ++j) o[j] = vtile[sh*32 + cchunk*8 + j][e];
        *(f16x8*)(dst + cchunk*8) = o;
    }
}

// ---------------------------------------------------------------------------
// Kernel 2: fc_w fp32 -> fp16
// ---------------------------------------------------------------------------
__global__ __launch_bounds__(256) void cvt_kernel(
    const float* __restrict__ src, _Float16* __restrict__ dst)
{
    long i = ((long)blockIdx.x*256 + threadIdx.x)*8;
    f16x8 o;
    #pragma unroll
    for (int j = 0; j < 8; ++j) o[j] = (_Float16)src[i + j];
    *(f16x8*)(dst + i) = o;
}

// ---------------------------------------------------------------------------
// Kernel 3: flash attention, 32x32 MFMA structure, KVBLK=128 (R11 config,
// the measured structural plateau: 158 us / ~870 TF).
// ---------------------------------------------------------------------------
__global__ __launch_bounds__(512, 2) void attn_kernel(
    const _Float16* __restrict__ qf,
    const _Float16* __restrict__ kf,
    const _Float16* __restrict__ vt,
    _Float16* __restrict__ ob)
{
    __shared__ char smem[131072];
    const int tid = threadIdx.x;
    const int lane = tid & 63;
    const int w = tid >> 6;                      // 0..7
    const int orig = blockIdx.x;                 // 512 blocks
    const int b = ((orig & 7) << 6) | (orig >> 3);  // bijective XCD swizzle
    const int nh = b >> 3;
    const int n = nh >> 4, h = nh & 15;
    const int qt = (b & 7)*8 + w;                // 0..63, 32 q-rows each
    const int q32 = lane & 31;                   // q-col / A-row index
    const int hl = lane >> 5;                    // lane half

    const _Float16* qb = qf + (long)nh*SEQ*ED;
    const char* kg = (const char*)(kf + (long)nh*SEQ*ED);   // row = 256 B
    const char* vg = (const char*)(vt + (long)nh*ED*SEQ);   // row = SEQ*2 B

    // Q fragments (B-operand): lane holds Q[qt*32+q32][e = 16j + 8*hl + i]
    f16x8 qfr[8];
    #pragma unroll
    for (int j = 0; j < 8; ++j)
        qfr[j] = *(const f16x8*)(qb + (long)(qt*32 + q32)*ED + 16*j + 8*hl);

    // hoisted staging constants (kt-invariant)
    const int srow = tid >> 4;                         // 0..31
    const int sc   = (tid & 15) ^ (srow & 15);         // XOR chunk swizzle
    const long koff = (long)srow*256  + sc*16;         // + i*8192 per round
    const long voff = (long)srow*4096 + sc*16;         // + i*131072 per round
    const int  ldst = tid*16;                          // + i*8192 per round

    // stage one 128-col K/V tile (K: 128 s-rows x 256B; V: 128 e-rows x 256B)
    auto stage = [&](int kt, int bsel) {
        char* Kl = smem + bsel*65536;
        char* Vl = Kl + 32768;
        const char* ksrc = kg + (long)kt*32768 + koff;
        const char* vsrc = vg + (long)kt*256   + voff;
        #pragma unroll
        for (int i = 0; i < 4; ++i)
            gload16(ksrc + i*8192, Kl + i*8192 + ldst);
        #pragma unroll
        for (int i = 0; i < 4; ++i)
            gload16(vsrc + (long)i*131072, Vl + i*8192 + ldst);
    };

    f32x16 acc[4];
    #pragma unroll
    for (int vv = 0; vv < 4; ++vv)
      #pragma unroll
      for (int i = 0; i < 16; ++i) acc[vv][i] = 0.f;
    float mrun = 0.f, lrun = 0.f;    // scores >= 0 (positive features)

    stage(0, 0);
    __syncthreads();

    const int kswz = q32 & 15;

    for (int kt = 0; kt < SEQ/128; ++kt) {
        const int cur = kt & 1;
        if (kt + 1 < SEQ/128) stage(kt + 1, cur ^ 1);
        const char* Kl = smem + cur*65536;
        const char* Vl = Kl + 32768;

        #pragma unroll
        for (int p = 0; p < 2; ++p) {
            // ---- QK^T: two 32x32 S^T tiles, C-init = -mrun ----
            const float nmr = -mrun;
            f32x16 s0, s1;
            #pragma unroll
            for (int i = 0; i < 16; ++i) { s0[i] = nmr; s1[i] = nmr; }
            const char* Kb = Kl + (p*64 + q32)*256;
            __builtin_amdgcn_s_setprio(1);
            #pragma unroll
            for (int j = 0; j < 8; ++j) {
                int off = (((hl + 2*j) & 15) ^ kswz) << 4;
                f16x8 k0 = *(const f16x8*)(Kb + off);
                f16x8 k1 = *(const f16x8*)(Kb + 8192 + off);
                s0 = __builtin_amdgcn_mfma_f32_32x32x16_f16(k0, qfr[j], s0, 0, 0, 0);
                s1 = __builtin_amdgcn_mfma_f32_32x32x16_f16(k1, qfr[j], s1, 0, 0, 0);
            }
            __builtin_amdgcn_s_setprio(0);

            // ---- relative max, defer-rescale THR=8 ----
            float mx = M3(s0[0], s0[1], s0[2]);
            mx = M3(mx, s0[3], s0[4]);   mx = M3(mx, s0[5], s0[6]);
            mx = M3(mx, s0[7], s0[8]);   mx = M3(mx, s0[9], s0[10]);
            mx = M3(mx, s0[11], s0[12]); mx = M3(mx, s0[13], s0[14]);
            mx = M3(mx, s0[15], s1[0]);  mx = M3(mx, s1[1], s1[2]);
            mx = M3(mx, s1[3], s1[4]);   mx = M3(mx, s1[5], s1[6]);
            mx = M3(mx, s1[7], s1[8]);   mx = M3(mx, s1[9], s1[10]);
            mx = M3(mx, s1[11], s1[12]); mx = M3(mx, s1[13], s1[14]);
            mx = fmaxf(mx, s1[15]);
            mx = fmaxf(mx, __shfl_xor(mx, 32, 64));      // combine lane halves
            if (__any(mx > 8.0f)) {                       // rare path
                float d = fmaxf(mx, 0.f);
                float corr = ex2(-d);
                mrun += d;
                lrun *= corr;
                #pragma unroll
                for (int vv = 0; vv < 4; ++vv)
                    #pragma unroll
                    for (int i = 0; i < 16; ++i) acc[vv][i] *= corr;
                #pragma unroll
                for (int i = 0; i < 16; ++i) { s0[i] -= d; s1[i] -= d; }
            }
            // P = exp2(s_rel); rsum via packed f16 adds
            int wreg[2][8];
            f16x2 psum = (f16x2){(_Float16)0.f, (_Float16)0.f};
            #pragma unroll
            for (int tW = 0; tW < 8; ++tW) {
                int pw = pk2(ex2(s0[2*tW]), ex2(s0[2*tW+1]));
                wreg[0][tW] = pw; psum += asf16x2(pw);
            }
            #pragma unroll
            for (int tW = 0; tW < 8; ++tW) {
                int pw = pk2(ex2(s1[2*tW]), ex2(s1[2*tW+1]));
                wreg[1][tW] = pw; psum += asf16x2(pw);
            }
            float rsum = (float)psum[0] + (float)psum[1];
            rsum += __shfl_xor(rsum, 32, 64);
            lrun += rsum;

            // ---- build PV B-operands: permlane32_swap pairs ----
            f16x8 pa[4];
            #pragma unroll
            for (int kk = 0; kk < 2; ++kk) {
                #pragma unroll
                for (int par = 0; par < 2; ++par) {
                    int a0 = wreg[kk][par*4 + 0], b0 = wreg[kk][par*4 + 2];
                    int a1 = wreg[kk][par*4 + 1], b1 = wreg[kk][par*4 + 3];
                    auto r0 = __builtin_amdgcn_permlane32_swap(a0, b0, false, false);
                    auto r1 = __builtin_amdgcn_permlane32_swap(a1, b1, false, false);
                    pa[kk*2 + par] = frag4(r0[0], r1[0], r0[1], r1[1]);
                }
            }

            // ---- PV: O^T += V^T · P  (4 ks slices × 4 v-subtiles) ----
            #pragma unroll
            for (int ks = 0; ks < 4; ++ks) {
                f16x8 vfr[4];
                #pragma unroll
                for (int vv = 0; vv < 4; ++vv) {
                    int vrow = vv*32 + q32;
                    int c0 = p*8 + ks*2 + hl;
                    vfr[vv] = *(const f16x8*)(Vl + vrow*256 + ((c0 ^ kswz) << 4));
                }
                __builtin_amdgcn_s_setprio(1);
                #pragma unroll
                for (int vv = 0; vv < 4; ++vv)
                    acc[vv] = __builtin_amdgcn_mfma_f32_32x32x16_f16(vfr[vv], pa[ks], acc[vv], 0, 0, 0);
                __builtin_amdgcn_s_setprio(0);
            }
        }
        __syncthreads();   // drains vmcnt (stage kt+1 done) + protects buffers
    }

    // ---- epilogue: O^T -> ob[n][q][h*128 + v] ----
    float inv = 1.0f / lrun;
    int q = qt*32 + q32;
    long base = ((long)n*SEQ + q)*FCK + h*ED;
    #pragma unroll
    for (int vv = 0; vv < 4; ++vv) {
        #pragma unroll
        for (int rg = 0; rg < 4; ++rg) {
            f16x4 o;
            #pragma unroll
            for (int i = 0; i < 4; ++i) o[i] = (_Float16)(acc[vv][rg*4 + i] * inv);
            *(f16x4*)(ob + base + vv*32 + 8*rg + 4*hl) = o;
        }
    }
}

// ---------------------------------------------------------------------------
// Kernel 4: out[8192,1024] = ob[8192,2048](fp16) @ fc_w^T(fp16) + fc_b, fp32.
// 128x128 tile, BK=64, LDS dbuf 64KB (2 blocks/CU). 4 waves (2x2).
// ---------------------------------------------------------------------------
__global__ __launch_bounds__(256) void fc_kernel(
    const _Float16* __restrict__ ob,
    const _Float16* __restrict__ wt,
    const float* __restrict__ fcb,
    float* __restrict__ out)
{
    __shared__ char smem[65536];            // 2 x (A 16KB + B 16KB)
    const int tid = threadIdx.x;
    const int lane = tid & 63;
    const int w = tid >> 6;                 // 0..3
    const int wm = w >> 1, wn = w & 1;      // 2x2 wave grid
    const int r = lane & 15, g = lane >> 4;

    const int orig = blockIdx.x;            // 512 blocks
    const int tile = ((orig & 7) << 6) | (orig >> 3);  // XCD-contiguous
    const int mt = tile >> 3;               // 0..63
    const int nt = tile & 7;                // 0..7

    const char* Ag = (const char*)(ob + (long)mt*128*FCK);
    const char* Bg = (const char*)(wt + (long)nt*128*FCK);

    // staging constants: thread t covers row rnd*32+(t>>3), chunk t&7
    const int srow = tid >> 3;              // 0..31 (row within round)
    const int schk = tid & 7;
    const int  ldst = tid*16;               // + rnd*4096
    const long goff = (long)srow*(FCK*2) + (schk ^ (srow & 7))*16;

    auto stage = [&](int kt, int bsel) {
        char* As = smem + bsel*32768;
        char* Bs = As + 16384;
        const char* asrc = Ag + (long)kt*128 + goff;
        const char* bsrc = Bg + (long)kt*128 + goff;
        #pragma unroll
        for (int rnd = 0; rnd < 4; ++rnd)
            gload16(asrc + (long)rnd*32*(FCK*2), As + rnd*4096 + ldst);
        #pragma unroll
        for (int rnd = 0; rnd < 4; ++rnd)
            gload16(bsrc + (long)rnd*32*(FCK*2), Bs + rnd*4096 + ldst);
    };

    f32x4 acc[4][4];
    #pragma unroll
    for (int u = 0; u < 4; ++u)
      #pragma unroll
      for (int v = 0; v < 4; ++v) acc[u][v] = (f32x4){0.f,0.f,0.f,0.f};

    stage(0, 0);
    __syncthreads();

    for (int kt = 0; kt < FCK/64; ++kt) {
        const int cur = kt & 1;
        if (kt + 1 < FCK/64) stage(kt + 1, cur ^ 1);
        const char* As = smem + cur*32768;
        const char* Bs = As + 16384;

        #pragma unroll
        for (int kk = 0; kk < 2; ++kk) {
            f16x8 afr[4], bfr[4];
            #pragma unroll
            for (int u = 0; u < 4; ++u) {
                int row = wm*64 + u*16 + r;
                afr[u] = *(const f16x8*)(As + row*128 + (((g + 4*kk) ^ (row & 7)) << 4));
            }
            #pragma unroll
            for (int v = 0; v < 4; ++v) {
                int row = wn*64 + v*16 + r;
                bfr[v] = *(const f16x8*)(Bs + row*128 + (((g + 4*kk) ^ (row & 7)) << 4));
            }
            __builtin_amdgcn_s_setprio(1);
            #pragma unroll
            for (int u = 0; u < 4; ++u)
              #pragma unroll
              for (int v = 0; v < 4; ++v)
                acc[u][v] = __builtin_amdgcn_mfma_f32_16x16x32_f16(afr[u], bfr[v], acc[u][v], 0, 0, 0);
            __builtin_amdgcn_s_setprio(0);
        }
        __syncthreads();
    }

    #pragma unroll
    for (int u = 0; u < 4; ++u)
      #pragma unroll
      for (int v = 0; v < 4; ++v) {
        int col = nt*128 + wn*64 + v*16 + r;
        float bias = fcb[col];
        #pragma unroll
        for (int i = 0; i < 4; ++i) {
            int row = mt*128 + wm*64 + u*16 + 4*g + i;
            out[(long)row*EMB + col] = acc[u][v][i] + bias;
        }
      }
}

// ---------------------------------------------------------------------------
extern "C" void kernel_launch(void* const* d_in, const int* in_sizes, int n_in,
                              void* d_out, int out_size, void* d_ws, size_t ws_size,
                              hipStream_t stream) {
    const float* vals = (const float*)d_in[0];
    const float* keys = (const float*)d_in[1];
    const float* qry  = (const float*)d_in[2];
    const float* fmw  = (const float*)d_in[3];
    const float* fmb  = (const float*)d_in[4];
    const float* fcw  = (const float*)d_in[5];
    const float* fcb  = (const float*)d_in[6];
    char* ws = (char*)d_ws;
    const long SZ = 33554432L;                       // 32 MB per fp16 tensor
    _Float16* qf = (_Float16*)(ws);
    _Float16* kf = (_Float16*)(ws + SZ);
    _Float16* vt = (_Float16*)(ws + 2*SZ);
    _Float16* ob = (_Float16*)(ws + 3*SZ);
    _Float16* wt = (_Float16*)(ws + 4*SZ);           // +4 MB
    float* out = (float*)d_out;

    fmap_kernel<<<dim3(2048), dim3(256), 0, stream>>>(vals, keys, qry, fmw, fmb, qf, kf, vt);
    cvt_kernel<<<dim3(1024), dim3(256), 0, stream>>>(fcw, wt);
    attn_kernel<<<dim3(512), dim3(512), 0, stream>>>(qf, kf, vt, ob);
    fc_kernel<<<dim3(512), dim3(256), 0, stream>>>(ob, wt, fcb, out);
}

// Round 17
// 245.294 us; speedup vs baseline: 1.1339x; 1.0065x over previous
//
#include <hip/hip_runtime.h>
#include <hip/hip_bf16.h>
#include <stdint.h>

#define N_B 4
#define SEQ 2048
#define NH 16
#define ED 128      // expanded feature dim per head
#define EMB 1024
#define FCK 2048    // NH*ED

typedef float f32x4 __attribute__((ext_vector_type(4)));
typedef float f32x16 __attribute__((ext_vector_type(16)));
typedef _Float16 f16x8 __attribute__((ext_vector_type(8)));
typedef _Float16 f16x4 __attribute__((ext_vector_type(4)));
typedef _Float16 f16x2 __attribute__((ext_vector_type(2)));
typedef __fp16 fp16v2 __attribute__((ext_vector_type(2)));

__device__ __forceinline__ void gload16(const void* g, void* l) {
    __builtin_amdgcn_global_load_lds(
        (const __attribute__((address_space(1))) uint32_t*)(g),
        (__attribute__((address_space(3))) uint32_t*)(l), 16, 0, 0);
}

__device__ __forceinline__ int pk2(float a, float b) {
    union { fp16v2 h; int i; } u;
    u.h = __builtin_amdgcn_cvt_pkrtz(a, b);
    return u.i;
}

__device__ __forceinline__ f16x2 asf16x2(int v) {
    union { int i; f16x2 h; } u; u.i = v; return u.h;
}

__device__ __forceinline__ f16x8 frag4(int d0, int d1, int d2, int d3) {
    union { int i[4]; f16x8 v; } u;
    u.i[0] = d0; u.i[1] = d1; u.i[2] = d2; u.i[3] = d3;
    return u.v;
}

// raw v_exp_f32 (inputs bounded; deep-negative -> 0 is correct)
__device__ __forceinline__ float ex2(float x) {
#if __has_builtin(__builtin_amdgcn_exp2f)
    return __builtin_amdgcn_exp2f(x);
#else
    return exp2f(x);
#endif
}

#define LOG2E 1.4426950408889634f
#define M3(a,b,c) fmaxf(fmaxf((a),(b)),(c))

// ---------------------------------------------------------------------------
// Kernel 1: feature map + inline V transpose. One block = (n, head, 64-s
// tile); wave w owns 16 s-rows. z ~fp32-exact via 3-term hi/lo MFMA.
// ALL outputs staged through the [64][136] LDS tile and written out with
// full coalescing: q/k as 256-B s-rows (R16 wrote 2-B scattered stores:
// 32 scalar stores/lane/tensor), V transposed as 128-B vt rows.
// ---------------------------------------------------------------------------
__global__ __launch_bounds__(256) void fmap_kernel(
    const float* __restrict__ vals, const float* __restrict__ keys,
    const float* __restrict__ qry,  const float* __restrict__ fmw,
    const float* __restrict__ fmb,
    _Float16* __restrict__ qf, _Float16* __restrict__ kf,
    _Float16* __restrict__ vt)
{
    __shared__ _Float16 tile[64][136];
    const int tid = threadIdx.x;
    const int lane = tid & 63;
    const int w = tid >> 6;            // 0..3
    const int b = blockIdx.x;          // 2048 = n(4) x h(16) x st(32)
    const int st = b & 31;
    const int h  = (b >> 5) & 15;
    const int n  = b >> 9;
    const int r = lane & 15;
    const int g = lane >> 4;

    f16x8 whf[4][2], wlf[4][2];
    #pragma unroll
    for (int te = 0; te < 4; ++te) {
      #pragma unroll
      for (int j = 0; j < 2; ++j) {
        const float* p = fmw + (te*16 + r)*64 + j*32 + 8*g;
        #pragma unroll
        for (int i = 0; i < 8; ++i) {
            float wv = p[i];
            _Float16 hi = (_Float16)wv;
            whf[te][j][i] = hi;
            wlf[te][j][i] = (_Float16)(wv - (float)hi);
        }
      }
    }
    float bias[4];
    #pragma unroll
    for (int te = 0; te < 4; ++te) bias[te] = fmb[te*16 + r];

    const float QSCL = 0.03125f * LOG2E;   // (1/sqrt(1024))*log2(e)

    const int s0 = st*64 + w*16;           // wave's s base
    const long rowoff = ((long)n*SEQ + s0 + r)*EMB + h*64;
    const float* srcs[3] = {qry, keys, vals};
    #pragma unroll
    for (int tens = 0; tens < 3; ++tens) {
        const float* src = srcs[tens] + rowoff;
        f16x8 ah[2], al[2];
        #pragma unroll
        for (int j = 0; j < 2; ++j) {
            #pragma unroll
            for (int i = 0; i < 8; ++i) {
                float x = src[j*32 + 8*g + i];
                _Float16 hi = (_Float16)x;
                ah[j][i] = hi;
                al[j][i] = (_Float16)(x - (float)hi);
            }
        }
        const float oscl = (tens == 0) ? QSCL : 1.0f;
        #pragma unroll
        for (int te = 0; te < 4; ++te) {
            f32x4 c = (f32x4){0.f,0.f,0.f,0.f};
            c = __builtin_amdgcn_mfma_f32_16x16x32_f16(ah[0], whf[te][0], c, 0, 0, 0);
            c = __builtin_amdgcn_mfma_f32_16x16x32_f16(ah[1], whf[te][1], c, 0, 0, 0);
            c = __builtin_amdgcn_mfma_f32_16x16x32_f16(ah[0], wlf[te][0], c, 0, 0, 0);
            c = __builtin_amdgcn_mfma_f32_16x16x32_f16(ah[1], wlf[te][1], c, 0, 0, 0);
            c = __builtin_amdgcn_mfma_f32_16x16x32_f16(al[0], whf[te][0], c, 0, 0, 0);
            c = __builtin_amdgcn_mfma_f32_16x16x32_f16(al[1], whf[te][1], c, 0, 0, 0);
            // lane holds z[s-row = 4g+i][e = te*16 + r]
            #pragma unroll
            for (int i = 0; i < 4; ++i) {
                float zl = (c[i] + bias[te]) * LOG2E;
                int e = te*16 + r;
                int srow = w*16 + 4*g + i;
                tile[srow][e]      = (_Float16)(ex2(zl)  * oscl);
                tile[srow][64 + e] = (_Float16)(ex2(-zl) * oscl);
            }
        }
        __syncthreads();
        if (tens < 2) {
            // coalesced s-row write: thread covers row tid>>2, 32-e chunk tid&3
            _Float16* dstb = (tens == 0 ? qf : kf) +
                (((long)(n*NH + h))*SEQ + st*64 + (tid >> 2))*ED + (tid & 3)*32;
            const _Float16* srcr = &tile[tid >> 2][(tid & 3)*32];
            #pragma unroll
            for (int ii = 0; ii < 4; ++ii)
                *(f16x8*)(dstb + ii*8) = *(const f16x8*)(srcr + ii*8);
        } else {
            // transposed write: vt[(n,h)][e][st*64 + s], full 128-B rows
            const int e  = tid >> 1;       // 0..127
            const int sh = tid & 1;        // s-half
            _Float16* dst = vt + ((long)(n*NH + h)*ED + e)*SEQ + st*64 + sh*32;
            #pragma unroll
            for (int cchunk = 0; cchunk < 4; ++cchunk) {
                f16x8 o;
                #pragma unroll
                for (int j = 0; j < 8; ++j) o[j] = tile[sh*32 + cchunk*8 + j][e];
                *(f16x8*)(dst + cchunk*8) = o;
            }
        }
        __syncthreads();   // protect tile before next tensor overwrites
    }
}

// ---------------------------------------------------------------------------
// Kernel 2: fc_w fp32 -> fp16
// ---------------------------------------------------------------------------
__global__ __launch_bounds__(256) void cvt_kernel(
    const float* __restrict__ src, _Float16* __restrict__ dst)
{
    long i = ((long)blockIdx.x*256 + threadIdx.x)*8;
    f16x8 o;
    #pragma unroll
    for (int j = 0; j < 8; ++j) o[j] = (_Float16)src[i + j];
    *(f16x8*)(dst + i) = o;
}

// ---------------------------------------------------------------------------
// Kernel 3: flash attention, 32x32 MFMA structure, KVBLK=128 (R11 config,
// the measured structural plateau: 158 us / ~870 TF).
// ---------------------------------------------------------------------------
__global__ __launch_bounds__(512, 2) void attn_kernel(
    const _Float16* __restrict__ qf,
    const _Float16* __restrict__ kf,
    const _Float16* __restrict__ vt,
    _Float16* __restrict__ ob)
{
    __shared__ char smem[131072];
    const int tid = threadIdx.x;
    const int lane = tid & 63;
    const int w = tid >> 6;                      // 0..7
    const int orig = blockIdx.x;                 // 512 blocks
    const int b = ((orig & 7) << 6) | (orig >> 3);  // bijective XCD swizzle
    const int nh = b >> 3;
    const int n = nh >> 4, h = nh & 15;
    const int qt = (b & 7)*8 + w;                // 0..63, 32 q-rows each
    const int q32 = lane & 31;                   // q-col / A-row index
    const int hl = lane >> 5;                    // lane half

    const _Float16* qb = qf + (long)nh*SEQ*ED;
    const char* kg = (const char*)(kf + (long)nh*SEQ*ED);   // row = 256 B
    const char* vg = (const char*)(vt + (long)nh*ED*SEQ);   // row = SEQ*2 B

    // Q fragments (B-operand): lane holds Q[qt*32+q32][e = 16j + 8*hl + i]
    f16x8 qfr[8];
    #pragma unroll
    for (int j = 0; j < 8; ++j)
        qfr[j] = *(const f16x8*)(qb + (long)(qt*32 + q32)*ED + 16*j + 8*hl);

    // hoisted staging constants (kt-invariant)
    const int srow = tid >> 4;                         // 0..31
    const int sc   = (tid & 15) ^ (srow & 15);         // XOR chunk swizzle
    const long koff = (long)srow*256  + sc*16;         // + i*8192 per round
    const long voff = (long)srow*4096 + sc*16;         // + i*131072 per round
    const int  ldst = tid*16;                          // + i*8192 per round

    // stage one 128-col K/V tile (K: 128 s-rows x 256B; V: 128 e-rows x 256B)
    auto stage = [&](int kt, int bsel) {
        char* Kl = smem + bsel*65536;
        char* Vl = Kl + 32768;
        const char* ksrc = kg + (long)kt*32768 + koff;
        const char* vsrc = vg + (long)kt*256   + voff;
        #pragma unroll
        for (int i = 0; i < 4; ++i)
            gload16(ksrc + i*8192, Kl + i*8192 + ldst);
        #pragma unroll
        for (int i = 0; i < 4; ++i)
            gload16(vsrc + (long)i*131072, Vl + i*8192 + ldst);
    };

    f32x16 acc[4];
    #pragma unroll
    for (int vv = 0; vv < 4; ++vv)
      #pragma unroll
      for (int i = 0; i < 16; ++i) acc[vv][i] = 0.f;
    float mrun = 0.f, lrun = 0.f;    // scores >= 0 (positive features)

    stage(0, 0);
    __syncthreads();

    const int kswz = q32 & 15;

    for (int kt = 0; kt < SEQ/128; ++kt) {
        const int cur = kt & 1;
        if (kt + 1 < SEQ/128) stage(kt + 1, cur ^ 1);
        const char* Kl = smem + cur*65536;
        const char* Vl = Kl + 32768;

        #pragma unroll
        for (int p = 0; p < 2; ++p) {
            // ---- QK^T: two 32x32 S^T tiles, C-init = -mrun ----
            const float nmr = -mrun;
            f32x16 s0, s1;
            #pragma unroll
            for (int i = 0; i < 16; ++i) { s0[i] = nmr; s1[i] = nmr; }
            const char* Kb = Kl + (p*64 + q32)*256;
            __builtin_amdgcn_s_setprio(1);
            #pragma unroll
            for (int j = 0; j < 8; ++j) {
                int off = (((hl + 2*j) & 15) ^ kswz) << 4;
                f16x8 k0 = *(const f16x8*)(Kb + off);
                f16x8 k1 = *(const f16x8*)(Kb + 8192 + off);
                s0 = __builtin_amdgcn_mfma_f32_32x32x16_f16(k0, qfr[j], s0, 0, 0, 0);
                s1 = __builtin_amdgcn_mfma_f32_32x32x16_f16(k1, qfr[j], s1, 0, 0, 0);
            }
            __builtin_amdgcn_s_setprio(0);

            // ---- relative max, defer-rescale THR=8 ----
            float mx = M3(s0[0], s0[1], s0[2]);
            mx = M3(mx, s0[3], s0[4]);   mx = M3(mx, s0[5], s0[6]);
            mx = M3(mx, s0[7], s0[8]);   mx = M3(mx, s0[9], s0[10]);
            mx = M3(mx, s0[11], s0[12]); mx = M3(mx, s0[13], s0[14]);
            mx = M3(mx, s0[15], s1[0]);  mx = M3(mx, s1[1], s1[2]);
            mx = M3(mx, s1[3], s1[4]);   mx = M3(mx, s1[5], s1[6]);
            mx = M3(mx, s1[7], s1[8]);   mx = M3(mx, s1[9], s1[10]);
            mx = M3(mx, s1[11], s1[12]); mx = M3(mx, s1[13], s1[14]);
            mx = fmaxf(mx, s1[15]);
            mx = fmaxf(mx, __shfl_xor(mx, 32, 64));      // combine lane halves
            if (__any(mx > 8.0f)) {                       // rare path
                float d = fmaxf(mx, 0.f);
                float corr = ex2(-d);
                mrun += d;
                lrun *= corr;
                #pragma unroll
                for (int vv = 0; vv < 4; ++vv)
                    #pragma unroll
                    for (int i = 0; i < 16; ++i) acc[vv][i] *= corr;
                #pragma unroll
                for (int i = 0; i < 16; ++i) { s0[i] -= d; s1[i] -= d; }
            }
            // P = exp2(s_rel); rsum via packed f16 adds
            int wreg[2][8];
            f16x2 psum = (f16x2){(_Float16)0.f, (_Float16)0.f};
            #pragma unroll
            for (int tW = 0; tW < 8; ++tW) {
                int pw = pk2(ex2(s0[2*tW]), ex2(s0[2*tW+1]));
                wreg[0][tW] = pw; psum += asf16x2(pw);
            }
            #pragma unroll
            for (int tW = 0; tW < 8; ++tW) {
                int pw = pk2(ex2(s1[2*tW]), ex2(s1[2*tW+1]));
                wreg[1][tW] = pw; psum += asf16x2(pw);
            }
            float rsum = (float)psum[0] + (float)psum[1];
            rsum += __shfl_xor(rsum, 32, 64);
            lrun += rsum;

            // ---- build PV B-operands: permlane32_swap pairs ----
            f16x8 pa[4];
            #pragma unroll
            for (int kk = 0; kk < 2; ++kk) {
                #pragma unroll
                for (int par = 0; par < 2; ++par) {
                    int a0 = wreg[kk][par*4 + 0], b0 = wreg[kk][par*4 + 2];
                    int a1 = wreg[kk][par*4 + 1], b1 = wreg[kk][par*4 + 3];
                    auto r0 = __builtin_amdgcn_permlane32_swap(a0, b0, false, false);
                    auto r1 = __builtin_amdgcn_permlane32_swap(a1, b1, false, false);
                    pa[kk*2 + par] = frag4(r0[0], r1[0], r0[1], r1[1]);
                }
            }

            // ---- PV: O^T += V^T · P  (4 ks slices × 4 v-subtiles) ----
            #pragma unroll
            for (int ks = 0; ks < 4; ++ks) {
                f16x8 vfr[4];
                #pragma unroll
                for (int vv = 0; vv < 4; ++vv) {
                    int vrow = vv*32 + q32;
                    int c0 = p*8 + ks*2 + hl;
                    vfr[vv] = *(const f16x8*)(Vl + vrow*256 + ((c0 ^ kswz) << 4));
                }
                __builtin_amdgcn_s_setprio(1);
                #pragma unroll
                for (int vv = 0; vv < 4; ++vv)
                    acc[vv] = __builtin_amdgcn_mfma_f32_32x32x16_f16(vfr[vv], pa[ks], acc[vv], 0, 0, 0);
                __builtin_amdgcn_s_setprio(0);
            }
        }
        __syncthreads();   // drains vmcnt (stage kt+1 done) + protects buffers
    }

    // ---- epilogue: O^T -> ob[n][q][h*128 + v] ----
    float inv = 1.0f / lrun;
    int q = qt*32 + q32;
    long base = ((long)n*SEQ + q)*FCK + h*ED;
    #pragma unroll
    for (int vv = 0; vv < 4; ++vv) {
        #pragma unroll
        for (int rg = 0; rg < 4; ++rg) {
            f16x4 o;
            #pragma unroll
            for (int i = 0; i < 4; ++i) o[i] = (_Float16)(acc[vv][rg*4 + i] * inv);
            *(f16x4*)(ob + base + vv*32 + 8*rg + 4*hl) = o;
        }
    }
}

// ---------------------------------------------------------------------------
// Kernel 4: out[8192,1024] = ob[8192,2048](fp16) @ fc_w^T(fp16) + fc_b, fp32.
// 128x128 tile, BK=64, LDS dbuf 64KB (2 blocks/CU). 4 waves (2x2).
// ---------------------------------------------------------------------------
__global__ __launch_bounds__(256) void fc_kernel(
    const _Float16* __restrict__ ob,
    const _Float16* __restrict__ wt,
    const float* __restrict__ fcb,
    float* __restrict__ out)
{
    __shared__ char smem[65536];            // 2 x (A 16KB + B 16KB)
    const int tid = threadIdx.x;
    const int lane = tid & 63;
    const int w = tid >> 6;                 // 0..3
    const int wm = w >> 1, wn = w & 1;      // 2x2 wave grid
    const int r = lane & 15, g = lane >> 4;

    const int orig = blockIdx.x;            // 512 blocks
    const int tile = ((orig & 7) << 6) | (orig >> 3);  // XCD-contiguous
    const int mt = tile >> 3;               // 0..63
    const int nt = tile & 7;                // 0..7

    const char* Ag = (const char*)(ob + (long)mt*128*FCK);
    const char* Bg = (const char*)(wt + (long)nt*128*FCK);

    // staging constants: thread t covers row rnd*32+(t>>3), chunk t&7
    const int srow = tid >> 3;              // 0..31 (row within round)
    const int schk = tid & 7;
    const int  ldst = tid*16;               // + rnd*4096
    const long goff = (long)srow*(FCK*2) + (schk ^ (srow & 7))*16;

    auto stage = [&](int kt, int bsel) {
        char* As = smem + bsel*32768;
        char* Bs = As + 16384;
        const char* asrc = Ag + (long)kt*128 + goff;
        const char* bsrc = Bg + (long)kt*128 + goff;
        #pragma unroll
        for (int rnd = 0; rnd < 4; ++rnd)
            gload16(asrc + (long)rnd*32*(FCK*2), As + rnd*4096 + ldst);
        #pragma unroll
        for (int rnd = 0; rnd < 4; ++rnd)
            gload16(bsrc + (long)rnd*32*(FCK*2), Bs + rnd*4096 + ldst);
    };

    f32x4 acc[4][4];
    #pragma unroll
    for (int u = 0; u < 4; ++u)
      #pragma unroll
      for (int v = 0; v < 4; ++v) acc[u][v] = (f32x4){0.f,0.f,0.f,0.f};

    stage(0, 0);
    __syncthreads();

    for (int kt = 0; kt < FCK/64; ++kt) {
        const int cur = kt & 1;
        if (kt + 1 < FCK/64) stage(kt + 1, cur ^ 1);
        const char* As = smem + cur*32768;
        const char* Bs = As + 16384;

        #pragma unroll
        for (int kk = 0; kk < 2; ++kk) {
            f16x8 afr[4], bfr[4];
            #pragma unroll
            for (int u = 0; u < 4; ++u) {
                int row = wm*64 + u*16 + r;
                afr[u] = *(const f16x8*)(As + row*128 + (((g + 4*kk) ^ (row & 7)) << 4));
            }
            #pragma unroll
            for (int v = 0; v < 4; ++v) {
                int row = wn*64 + v*16 + r;
                bfr[v] = *(const f16x8*)(Bs + row*128 + (((g + 4*kk) ^ (row & 7)) << 4));
            }
            __builtin_amdgcn_s_setprio(1);
            #pragma unroll
            for (int u = 0; u < 4; ++u)
              #pragma unroll
              for (int v = 0; v < 4; ++v)
                acc[u][v] = __builtin_amdgcn_mfma_f32_16x16x32_f16(afr[u], bfr[v], acc[u][v], 0, 0, 0);
            __builtin_amdgcn_s_setprio(0);
        }
        __syncthreads();
    }

    #pragma unroll
    for (int u = 0; u < 4; ++u)
      #pragma unroll
      for (int v = 0; v < 4; ++v) {
        int col = nt*128 + wn*64 + v*16 + r;
        float bias = fcb[col];
        #pragma unroll
        for (int i = 0; i < 4; ++i) {
            int row = mt*128 + wm*64 + u*16 + 4*g + i;
            out[(long)row*EMB + col] = acc[u][v][i] + bias;
        }
      }
}

// ---------------------------------------------------------------------------
extern "C" void kernel_launch(void* const* d_in, const int* in_sizes, int n_in,
                              void* d_out, int out_size, void* d_ws, size_t ws_size,
                              hipStream_t stream) {
    const float* vals = (const float*)d_in[0];
    const float* keys = (const float*)d_in[1];
    const float* qry  = (const float*)d_in[2];
    const float* fmw  = (const float*)d_in[3];
    const float* fmb  = (const float*)d_in[4];
    const float* fcw  = (const float*)d_in[5];
    const float* fcb  = (const float*)d_in[6];
    char* ws = (char*)d_ws;
    const long SZ = 33554432L;                       // 32 MB per fp16 tensor
    _Float16* qf = (_Float16*)(ws);
    _Float16* kf = (_Float16*)(ws + SZ);
    _Float16* vt = (_Float16*)(ws + 2*SZ);
    _Float16* ob = (_Float16*)(ws + 3*SZ);
    _Float16* wt = (_Float16*)(ws + 4*SZ);           // +4 MB
    float* out = (float*)d_out;

    fmap_kernel<<<dim3(2048), dim3(256), 0, stream>>>(vals, keys, qry, fmw, fmb, qf, kf, vt);
    cvt_kernel<<<dim3(1024), dim3(256), 0, stream>>>(fcw, wt);
    attn_kernel<<<dim3(512), dim3(512), 0, stream>>>(qf, kf, vt, ob);
    fc_kernel<<<dim3(512), dim3(256), 0, stream>>>(ob, wt, fcb, out);
}